// Round 4
// baseline (208.073 us; speedup 1.0000x reference)
//
#include <hip/hip_runtime.h>
#include <stdint.h>

#define H 8
#define DH 96
#define L 2048
#define NB 2
#define D 768

typedef unsigned short u16;
typedef unsigned int u32;
typedef __attribute__((ext_vector_type(8))) __bf16 bf16x8;
typedef __attribute__((ext_vector_type(4))) float f32x4;
typedef __attribute__((ext_vector_type(4))) u32 u32x4;

// softmax scale folded with log2(e): 96^-0.5 * 1.4426950408889634
#define QSCALE 0.14724444f

static __device__ __forceinline__ u16 f2bf(float f) {
  union { __bf16 h; u16 u; } v;
  v.h = (__bf16)f;   // RNE cvt, compiler emits native bf16 convert
  return v.u;
}

// load 8 contiguous f32 and round-to-nearest-even to bf16x8
static __device__ __forceinline__ bf16x8 cvt8(const float* p) {
  f32x4 a = *(const f32x4*)p;
  f32x4 b = *(const f32x4*)(p + 4);
  bf16x8 r;
  r[0] = (__bf16)a[0]; r[1] = (__bf16)a[1]; r[2] = (__bf16)a[2]; r[3] = (__bf16)a[3];
  r[4] = (__bf16)b[0]; r[5] = (__bf16)b[1]; r[6] = (__bf16)b[2]; r[7] = (__bf16)b[3];
  return r;
}

// ---------------------------------------------------------------------------
// Fused QKV projection + RoPE (z=0: Q, z=1: K, z=2: V->V^T)
// A, W are float32; converted to bf16 at LDS staging. GEMM-BT:
// out[row,col] = sum_k A[row,k]*W[col,k]; M=4096, N=768, K=768.
// 128x128 tile, 4 waves (2x2 of 64x64), BK=32, 16x16x32 bf16 MFMA.
// Q output is pre-scaled by QSCALE (softmax scale in base-2 units).
// ---------------------------------------------------------------------------
__global__ __launch_bounds__(256, 2)
void proj_qkv(const float* __restrict__ Qin, const float* __restrict__ Kin,
              const float* __restrict__ Vin,
              const float* __restrict__ Wq, const float* __restrict__ Wk,
              const float* __restrict__ Wv,
              const float* __restrict__ cq, const float* __restrict__ ck,
              u16* __restrict__ qo, u16* __restrict__ ko, u16* __restrict__ vo)
{
  __shared__ u16 a_lds[128 * 40];   // [128][32] padded to 40
  __shared__ u16 b_lds[128 * 40];
  const int tid = threadIdx.x;
  const int lane = tid & 63;
  const int w = tid >> 6;
  const int wr = w >> 1, wc = w & 1;
  const int z = blockIdx.z;
  const int row0 = blockIdx.y * 128;
  const int col0 = blockIdx.x * 128;

  const float* A = (z == 0) ? Qin : ((z == 1) ? Kin : Vin);
  const float* W = (z == 0) ? Wq : ((z == 1) ? Wk : Wv);

  f32x4 acc[4][4] = {};

  const int srow = tid >> 2;         // 0..63
  const int scol = (tid & 3) * 8;    // 0,8,16,24 elements
  const float* Ab = A + (size_t)row0 * D;
  const float* Wb = W + (size_t)col0 * D;
  const int fr = lane & 15;
  const int fk = (lane >> 4) * 8;

  for (int k0 = 0; k0 < D; k0 += 32) {
    __syncthreads();
    bf16x8 va0 = cvt8(Ab + (size_t)srow * D + k0 + scol);
    bf16x8 va1 = cvt8(Ab + (size_t)(srow + 64) * D + k0 + scol);
    bf16x8 vb0 = cvt8(Wb + (size_t)srow * D + k0 + scol);
    bf16x8 vb1 = cvt8(Wb + (size_t)(srow + 64) * D + k0 + scol);
    *(bf16x8*)(a_lds + srow * 40 + scol) = va0;
    *(bf16x8*)(a_lds + (srow + 64) * 40 + scol) = va1;
    *(bf16x8*)(b_lds + srow * 40 + scol) = vb0;
    *(bf16x8*)(b_lds + (srow + 64) * 40 + scol) = vb1;
    __syncthreads();
    bf16x8 af[4], bfr[4];
#pragma unroll
    for (int m = 0; m < 4; m++)
      af[m] = *(const bf16x8*)(a_lds + (wr * 64 + m * 16 + fr) * 40 + fk);
#pragma unroll
    for (int n = 0; n < 4; n++)
      bfr[n] = *(const bf16x8*)(b_lds + (wc * 64 + n * 16 + fr) * 40 + fk);
#pragma unroll
    for (int m = 0; m < 4; m++)
#pragma unroll
      for (int n = 0; n < 4; n++)
        acc[m][n] = __builtin_amdgcn_mfma_f32_16x16x32_bf16(af[m], bfr[n], acc[m][n], 0, 0, 0);
  }

  if (z == 2) {
    // store V transposed: vt[((b*H + h)*96 + dd) * L + l]
#pragma unroll
    for (int m = 0; m < 4; m++) {
      int rbase = row0 + wr * 64 + m * 16 + (lane >> 4) * 4;
#pragma unroll
      for (int n = 0; n < 4; n++) {
        int c = col0 + wc * 64 + n * 16 + fr;
        int hh = c / DH, dd = c % DH;
#pragma unroll
        for (int r = 0; r < 4; r++) {
          int row = rbase + r;
          int b = row >> 11, l = row & (L - 1);
          vo[((size_t)((b * H + hh) * DH + dd)) * L + l] = f2bf(acc[m][n][r]);
        }
      }
    }
  } else {
    // RoPE-3D epilogue. Column blocks of 32 never cross a head boundary
    // (96 = 3*32); rotate-half partner (dd, dd+16) = fragments (n, n+1)
    // at the same lane. Store q/k as [B,H,L,96]; q pre-scaled by QSCALE.
    const float* coords = (z == 0) ? cq : ck;
    u16* outp = (z == 0) ? qo : ko;
    const float postscale = (z == 0) ? QSCALE : 1.0f;
#pragma unroll
    for (int m = 0; m < 4; m++) {
      int rbase = row0 + wr * 64 + m * 16 + (lane >> 4) * 4;
#pragma unroll
      for (int np = 0; np < 2; np++) {
        int n1 = np * 2;
        int c1 = col0 + wc * 64 + n1 * 16 + fr;
        int hh = c1 / DH;
        int dd1 = c1 % DH;
        int axis = dd1 / 32;
        int j = dd1 & 15;
        // inv_freq = 10000^(-j/16) = 2^(-j*log2(10000)/16)
        float invf = exp2f(-(float)j * 0.83048202372184058f);
#pragma unroll
        for (int r = 0; r < 4; r++) {
          int row = rbase + r;
          int b = row >> 11, l = row & (L - 1);
          float coord = coords[((size_t)(b * L + l)) * 3 + axis];
          float ang = coord * invf;
          float sn = __sinf(ang), cs = __cosf(ang);
          float x1 = acc[m][n1][r], x2 = acc[m][n1 + 1][r];
          size_t base = ((size_t)((b * H + hh) * L + l)) * DH;
          outp[base + dd1] = f2bf((x1 * cs - x2 * sn) * postscale);
          outp[base + dd1 + 16] = f2bf((x1 * sn + x2 * cs) * postscale);
        }
      }
    }
  }
}

// ---------------------------------------------------------------------------
// Flash attention: one block = 64 q-rows of one (b,h); 4 waves x 16 rows.
// K/V tiles of 64 staged in LDS (padded strides: K 104, V^T 72, P 88 —
// all <=2-way bank aliasing); online softmax in base-2 (q pre-scaled).
// ---------------------------------------------------------------------------
#define KSTR 104
#define PSTR 88
__global__ __launch_bounds__(256, 2)
void attn_fwd(const u16* __restrict__ q_ws, const u16* __restrict__ k_ws,
              const u16* __restrict__ vt_ws, u16* __restrict__ ao)
{
  __shared__ u16 k_lds[64 * KSTR];
  __shared__ u16 vt_lds[96 * 72];       // [96][64] padded to 72
  __shared__ u16 p_lds[4][16 * PSTR];   // per-wave [16][64]
  const int tid = threadIdx.x;
  const int lane = tid & 63;
  const int w = tid >> 6;
  const int bh = blockIdx.y;
  const int q0 = blockIdx.x * 64;

  const int fr = lane & 15;
  const int fko = (lane >> 4) * 8;

  // Q fragments held in registers for the whole block (A-frag layout)
  bf16x8 qf[3];
  const u16* qbase = q_ws + ((size_t)bh * L + q0 + w * 16 + fr) * DH;
#pragma unroll
  for (int ks = 0; ks < 3; ks++)
    qf[ks] = *(const bf16x8*)(qbase + ks * 32 + fko);

  f32x4 o[6] = {};
  float m_r[4], l_r[4];
#pragma unroll
  for (int r = 0; r < 4; r++) { m_r[r] = -1e30f; l_r[r] = 0.f; }

  const u16* kbase = k_ws + (size_t)bh * L * DH;
  const u16* vtbase = vt_ws + (size_t)bh * DH * L;

  for (int kt = 0; kt < L; kt += 64) {
    __syncthreads();
    // stage K tile [64][96]: 768 16B-chunks over 256 threads
    {
      int ch = tid;
#pragma unroll
      for (int it = 0; it < 3; it++, ch += 256) {
        int row = ch / 12, off = (ch % 12) * 8;
        *(u32x4*)(k_lds + row * KSTR + off) =
            *(const u32x4*)(kbase + (size_t)(kt + row) * DH + off);
      }
      int ch2 = tid;  // V^T tile [96][64]: 768 chunks
#pragma unroll
      for (int it = 0; it < 3; it++, ch2 += 256) {
        int row = ch2 >> 3, off = (ch2 & 7) * 8;
        *(u32x4*)(vt_lds + row * 72 + off) =
            *(const u32x4*)(vtbase + (size_t)row * L + kt + off);
      }
    }
    __syncthreads();

    // S = Q K^T : 4 n-frags x 3 k-steps (s is pre-scaled, base-2 units)
    f32x4 s[4] = {};
#pragma unroll
    for (int n = 0; n < 4; n++)
#pragma unroll
      for (int ks = 0; ks < 3; ks++) {
        bf16x8 kf = *(const bf16x8*)(k_lds + (n * 16 + fr) * KSTR + ks * 32 + fko);
        s[n] = __builtin_amdgcn_mfma_f32_16x16x32_bf16(qf[ks], kf, s[n], 0, 0, 0);
      }

    // online softmax (rows live on regs r, spread over 16 lanes)
    float mnew[4], alpha[4];
#pragma unroll
    for (int r = 0; r < 4; r++) {
      float mx = fmaxf(fmaxf(s[0][r], s[1][r]), fmaxf(s[2][r], s[3][r]));
#pragma unroll
      for (int d = 1; d < 16; d <<= 1)
        mx = fmaxf(mx, __shfl_xor(mx, d));
      float mn = fmaxf(m_r[r], mx);
      alpha[r] = exp2f(m_r[r] - mn);
      m_r[r] = mn;
      mnew[r] = mn;
    }
#pragma unroll
    for (int r = 0; r < 4; r++) {
      float rs = 0.f;
#pragma unroll
      for (int n = 0; n < 4; n++) {
        float p = exp2f(s[n][r] - mnew[r]);
        rs += p;
        p_lds[w][((lane >> 4) * 4 + r) * PSTR + n * 16 + fr] = f2bf(p);
      }
#pragma unroll
      for (int d = 1; d < 16; d <<= 1)
        rs += __shfl_xor(rs, d);
      l_r[r] = l_r[r] * alpha[r] + rs;
    }
#pragma unroll
    for (int nf = 0; nf < 6; nf++)
#pragma unroll
      for (int r = 0; r < 4; r++)
        o[nf][r] *= alpha[r];

    // PV: A = P (own wave's LDS rows), B = V^T tile
#pragma unroll
    for (int ks = 0; ks < 2; ks++) {
      bf16x8 pf = *(const bf16x8*)(&p_lds[w][fr * PSTR + ks * 32 + fko]);
#pragma unroll
      for (int nf = 0; nf < 6; nf++) {
        bf16x8 vf = *(const bf16x8*)(vt_lds + (nf * 16 + fr) * 72 + ks * 32 + fko);
        o[nf] = __builtin_amdgcn_mfma_f32_16x16x32_bf16(pf, vf, o[nf], 0, 0, 0);
      }
    }
  }

  // epilogue: ao[b, l, h*96 + dd], bf16
  const int b = bh >> 3, hh = bh & 7;
#pragma unroll
  for (int r = 0; r < 4; r++) {
    int l = q0 + w * 16 + (lane >> 4) * 4 + r;
    float inv = 1.f / l_r[r];
    size_t base = ((size_t)(b * L + l)) * D + hh * DH;
#pragma unroll
    for (int nf = 0; nf < 6; nf++)
      ao[base + nf * 16 + fr] = f2bf(o[nf][r] * inv);
  }
}

// ---------------------------------------------------------------------------
// Output projection: out = AO @ Wo^T; AO is bf16 ws, Wo is f32, out FLOAT32.
// ---------------------------------------------------------------------------
__global__ __launch_bounds__(256, 2)
void gemm_out(const u16* __restrict__ A, const float* __restrict__ W,
              float* __restrict__ out)
{
  __shared__ u16 a_lds[128 * 40];
  __shared__ u16 b_lds[128 * 40];
  const int tid = threadIdx.x;
  const int lane = tid & 63;
  const int w = tid >> 6;
  const int wr = w >> 1, wc = w & 1;
  const int row0 = blockIdx.y * 128;
  const int col0 = blockIdx.x * 128;

  f32x4 acc[4][4] = {};
  const int srow = tid >> 2;
  const int scol = (tid & 3) * 8;
  const u16* Ab = A + (size_t)row0 * D;
  const float* Wb = W + (size_t)col0 * D;
  const int fr = lane & 15;
  const int fk = (lane >> 4) * 8;

  for (int k0 = 0; k0 < D; k0 += 32) {
    __syncthreads();
    bf16x8 va0 = *(const bf16x8*)(Ab + (size_t)srow * D + k0 + scol);
    bf16x8 va1 = *(const bf16x8*)(Ab + (size_t)(srow + 64) * D + k0 + scol);
    bf16x8 vb0 = cvt8(Wb + (size_t)srow * D + k0 + scol);
    bf16x8 vb1 = cvt8(Wb + (size_t)(srow + 64) * D + k0 + scol);
    *(bf16x8*)(a_lds + srow * 40 + scol) = va0;
    *(bf16x8*)(a_lds + (srow + 64) * 40 + scol) = va1;
    *(bf16x8*)(b_lds + srow * 40 + scol) = vb0;
    *(bf16x8*)(b_lds + (srow + 64) * 40 + scol) = vb1;
    __syncthreads();
    bf16x8 af[4], bfr[4];
#pragma unroll
    for (int m = 0; m < 4; m++)
      af[m] = *(const bf16x8*)(a_lds + (wr * 64 + m * 16 + fr) * 40 + fk);
#pragma unroll
    for (int n = 0; n < 4; n++)
      bfr[n] = *(const bf16x8*)(b_lds + (wc * 64 + n * 16 + fr) * 40 + fk);
#pragma unroll
    for (int m = 0; m < 4; m++)
#pragma unroll
      for (int n = 0; n < 4; n++)
        acc[m][n] = __builtin_amdgcn_mfma_f32_16x16x32_bf16(af[m], bfr[n], acc[m][n], 0, 0, 0);
  }

#pragma unroll
  for (int m = 0; m < 4; m++) {
    int rbase = row0 + wr * 64 + m * 16 + (lane >> 4) * 4;
#pragma unroll
    for (int n = 0; n < 4; n++) {
      int c = col0 + wc * 64 + n * 16 + fr;
#pragma unroll
      for (int r = 0; r < 4; r++)
        out[(size_t)(rbase + r) * D + c] = acc[m][n][r];
    }
  }
}

extern "C" void kernel_launch(void* const* d_in, const int* in_sizes, int n_in,
                              void* d_out, int out_size, void* d_ws, size_t ws_size,
                              hipStream_t stream) {
  (void)in_sizes; (void)n_in; (void)out_size;
  const float* Qin = (const float*)d_in[0];
  const float* Kin = (const float*)d_in[1];
  const float* Vin = (const float*)d_in[2];
  const float* cq  = (const float*)d_in[3];
  const float* ck  = (const float*)d_in[4];
  const float* Wq  = (const float*)d_in[5];
  const float* Wk  = (const float*)d_in[6];
  const float* Wv  = (const float*)d_in[7];
  const float* Wo  = (const float*)d_in[8];
  float* out = (float*)d_out;

  const size_t per = (size_t)NB * H * L * DH;  // 3,145,728 elems
  if (ws_size < 4 * per * sizeof(u16)) return;

  u16* q_ws  = (u16*)d_ws;
  u16* k_ws  = q_ws + per;
  u16* vt_ws = k_ws + per;
  u16* ao_ws = vt_ws + per;

  dim3 blk(256);
  proj_qkv<<<dim3(D / 128, (NB * L) / 128, 3), blk, 0, stream>>>(
      Qin, Kin, Vin, Wq, Wk, Wv, cq, ck, q_ws, k_ws, vt_ws);
  attn_fwd<<<dim3(L / 64, NB * H), blk, 0, stream>>>(q_ws, k_ws, vt_ws, ao_ws);
  gemm_out<<<dim3(D / 128, (NB * L) / 128), blk, 0, stream>>>(ao_ws, Wo, out);
}

// Round 5
// 156.456 us; speedup vs baseline: 1.3299x; 1.3299x over previous
//
#include <hip/hip_runtime.h>
#include <stdint.h>

#define H 8
#define DH 96
#define L 2048
#define NB 2
#define D 768

typedef unsigned short u16;
typedef unsigned int u32;
typedef __attribute__((ext_vector_type(8))) __bf16 bf16x8;
typedef __attribute__((ext_vector_type(4))) float f32x4;
typedef __attribute__((ext_vector_type(4))) u32 u32x4;

// softmax scale folded with log2(e): 96^-0.5 * 1.4426950408889634
#define QSCALE 0.14724444f

static __device__ __forceinline__ u16 f2bf(float f) {
  union { __bf16 h; u16 u; } v;
  v.h = (__bf16)f;
  return v.u;
}

// load 8 contiguous f32 and round-to-nearest-even to bf16x8
static __device__ __forceinline__ bf16x8 cvt8(const float* p) {
  f32x4 a = *(const f32x4*)p;
  f32x4 b = *(const f32x4*)(p + 4);
  bf16x8 r;
  r[0] = (__bf16)a[0]; r[1] = (__bf16)a[1]; r[2] = (__bf16)a[2]; r[3] = (__bf16)a[3];
  r[4] = (__bf16)b[0]; r[5] = (__bf16)b[1]; r[6] = (__bf16)b[2]; r[7] = (__bf16)b[3];
  return r;
}

// ---------------------------------------------------------------------------
// Fused QKV projection + RoPE (z=0: Q, z=1: K, z=2: V->V^T)  — unchanged.
// ---------------------------------------------------------------------------
__global__ __launch_bounds__(256, 2)
void proj_qkv(const float* __restrict__ Qin, const float* __restrict__ Kin,
              const float* __restrict__ Vin,
              const float* __restrict__ Wq, const float* __restrict__ Wk,
              const float* __restrict__ Wv,
              const float* __restrict__ cq, const float* __restrict__ ck,
              u16* __restrict__ qo, u16* __restrict__ ko, u16* __restrict__ vo)
{
  __shared__ u16 a_lds[128 * 40];
  __shared__ u16 b_lds[128 * 40];
  const int tid = threadIdx.x;
  const int lane = tid & 63;
  const int w = tid >> 6;
  const int wr = w >> 1, wc = w & 1;
  const int z = blockIdx.z;
  const int row0 = blockIdx.y * 128;
  const int col0 = blockIdx.x * 128;

  const float* A = (z == 0) ? Qin : ((z == 1) ? Kin : Vin);
  const float* W = (z == 0) ? Wq : ((z == 1) ? Wk : Wv);

  f32x4 acc[4][4] = {};

  const int srow = tid >> 2;
  const int scol = (tid & 3) * 8;
  const float* Ab = A + (size_t)row0 * D;
  const float* Wb = W + (size_t)col0 * D;
  const int fr = lane & 15;
  const int fk = (lane >> 4) * 8;

  for (int k0 = 0; k0 < D; k0 += 32) {
    __syncthreads();
    bf16x8 va0 = cvt8(Ab + (size_t)srow * D + k0 + scol);
    bf16x8 va1 = cvt8(Ab + (size_t)(srow + 64) * D + k0 + scol);
    bf16x8 vb0 = cvt8(Wb + (size_t)srow * D + k0 + scol);
    bf16x8 vb1 = cvt8(Wb + (size_t)(srow + 64) * D + k0 + scol);
    *(bf16x8*)(a_lds + srow * 40 + scol) = va0;
    *(bf16x8*)(a_lds + (srow + 64) * 40 + scol) = va1;
    *(bf16x8*)(b_lds + srow * 40 + scol) = vb0;
    *(bf16x8*)(b_lds + (srow + 64) * 40 + scol) = vb1;
    __syncthreads();
    bf16x8 af[4], bfr[4];
#pragma unroll
    for (int m = 0; m < 4; m++)
      af[m] = *(const bf16x8*)(a_lds + (wr * 64 + m * 16 + fr) * 40 + fk);
#pragma unroll
    for (int n = 0; n < 4; n++)
      bfr[n] = *(const bf16x8*)(b_lds + (wc * 64 + n * 16 + fr) * 40 + fk);
#pragma unroll
    for (int m = 0; m < 4; m++)
#pragma unroll
      for (int n = 0; n < 4; n++)
        acc[m][n] = __builtin_amdgcn_mfma_f32_16x16x32_bf16(af[m], bfr[n], acc[m][n], 0, 0, 0);
  }

  if (z == 2) {
#pragma unroll
    for (int m = 0; m < 4; m++) {
      int rbase = row0 + wr * 64 + m * 16 + (lane >> 4) * 4;
#pragma unroll
      for (int n = 0; n < 4; n++) {
        int c = col0 + wc * 64 + n * 16 + fr;
        int hh = c / DH, dd = c % DH;
#pragma unroll
        for (int r = 0; r < 4; r++) {
          int row = rbase + r;
          int b = row >> 11, l = row & (L - 1);
          vo[((size_t)((b * H + hh) * DH + dd)) * L + l] = f2bf(acc[m][n][r]);
        }
      }
    }
  } else {
    const float* coords = (z == 0) ? cq : ck;
    u16* outp = (z == 0) ? qo : ko;
    const float postscale = (z == 0) ? QSCALE : 1.0f;
#pragma unroll
    for (int m = 0; m < 4; m++) {
      int rbase = row0 + wr * 64 + m * 16 + (lane >> 4) * 4;
#pragma unroll
      for (int np = 0; np < 2; np++) {
        int n1 = np * 2;
        int c1 = col0 + wc * 64 + n1 * 16 + fr;
        int hh = c1 / DH;
        int dd1 = c1 % DH;
        int axis = dd1 / 32;
        int j = dd1 & 15;
        float invf = exp2f(-(float)j * 0.83048202372184058f);
#pragma unroll
        for (int r = 0; r < 4; r++) {
          int row = rbase + r;
          int b = row >> 11, l = row & (L - 1);
          float coord = coords[((size_t)(b * L + l)) * 3 + axis];
          float ang = coord * invf;
          float sn = __sinf(ang), cs = __cosf(ang);
          float x1 = acc[m][n1][r], x2 = acc[m][n1 + 1][r];
          size_t base = ((size_t)((b * H + hh) * L + l)) * DH;
          outp[base + dd1] = f2bf((x1 * cs - x2 * sn) * postscale);
          outp[base + dd1 + 16] = f2bf((x1 * sn + x2 * cs) * postscale);
        }
      }
    }
  }
}

// ---------------------------------------------------------------------------
// Flash attention with register-prefetch + double-buffered K/V LDS.
// Tile t+1's global loads issue BEFORE tile t's compute (T14 async-stage):
// L2/HBM latency hides under QK/softmax/PV. 2 barriers per tile, but no
// vmcnt(0) drain inside the compute path.
// ---------------------------------------------------------------------------
#define KSTR 104
#define VSTR 72
#define PSTR 88
#define NT   (L / 64)
__global__ __launch_bounds__(256, 2)
void attn_fwd(const u16* __restrict__ q_ws, const u16* __restrict__ k_ws,
              const u16* __restrict__ vt_ws, u16* __restrict__ ao)
{
  __shared__ u16 k_lds[2][64 * KSTR];
  __shared__ u16 vt_lds[2][96 * VSTR];
  __shared__ u16 p_lds[4][16 * PSTR];
  const int tid = threadIdx.x;
  const int lane = tid & 63;
  const int w = tid >> 6;
  const int bh = blockIdx.y;
  const int q0 = blockIdx.x * 64;

  const int fr = lane & 15;
  const int fko = (lane >> 4) * 8;

  // loop-invariant staging offsets (3 K-chunks + 3 V-chunks per thread)
  int kg_off[3], kl_off[3], vg_off[3], vl_off[3];
#pragma unroll
  for (int it = 0; it < 3; it++) {
    int ch = tid + it * 256;
    int krow = ch / 12, koff = (ch % 12) * 8;
    kg_off[it] = krow * DH + koff;        // global: + kt*DH
    kl_off[it] = krow * KSTR + koff;
    int vrow = ch >> 3, voff = (ch & 7) * 8;
    vg_off[it] = vrow * L + voff;         // global: + kt
    vl_off[it] = vrow * VSTR + voff;
  }

  // Q fragments in registers for the whole block
  bf16x8 qf[3];
  const u16* qbase = q_ws + ((size_t)bh * L + q0 + w * 16 + fr) * DH;
#pragma unroll
  for (int ks = 0; ks < 3; ks++)
    qf[ks] = *(const bf16x8*)(qbase + ks * 32 + fko);

  f32x4 o[6] = {};
  float m_r[4], l_r[4];
#pragma unroll
  for (int r = 0; r < 4; r++) { m_r[r] = -1e30f; l_r[r] = 0.f; }

  const u16* kbase = k_ws + (size_t)bh * L * DH;
  const u16* vtbase = vt_ws + (size_t)bh * DH * L;

  u32x4 kreg[3], vreg[3];
  // prologue: tile 0 -> regs -> LDS buf 0
#pragma unroll
  for (int it = 0; it < 3; it++) {
    kreg[it] = *(const u32x4*)(kbase + kg_off[it]);
    vreg[it] = *(const u32x4*)(vtbase + vg_off[it]);
  }
#pragma unroll
  for (int it = 0; it < 3; it++) {
    *(u32x4*)(&k_lds[0][kl_off[it]]) = kreg[it];
    *(u32x4*)(&vt_lds[0][vl_off[it]]) = vreg[it];
  }
  __syncthreads();

  int cur = 0;
  for (int t = 0; t < NT; t++) {
    // issue next tile's global loads (latency hides under compute below)
    if (t + 1 < NT) {
      const u16* kb = kbase + (size_t)(t + 1) * 64 * DH;
      const u16* vb = vtbase + (t + 1) * 64;
#pragma unroll
      for (int it = 0; it < 3; it++) {
        kreg[it] = *(const u32x4*)(kb + kg_off[it]);
        vreg[it] = *(const u32x4*)(vb + vg_off[it]);
      }
    }

    // S = Q K^T (pre-scaled, base-2 units)
    f32x4 s[4] = {};
#pragma unroll
    for (int n = 0; n < 4; n++)
#pragma unroll
      for (int ks = 0; ks < 3; ks++) {
        bf16x8 kf = *(const bf16x8*)(&k_lds[cur][(n * 16 + fr) * KSTR + ks * 32 + fko]);
        s[n] = __builtin_amdgcn_mfma_f32_16x16x32_bf16(qf[ks], kf, s[n], 0, 0, 0);
      }

    // online softmax
    float mnew[4], alpha[4];
#pragma unroll
    for (int r = 0; r < 4; r++) {
      float mx = fmaxf(fmaxf(s[0][r], s[1][r]), fmaxf(s[2][r], s[3][r]));
#pragma unroll
      for (int d = 1; d < 16; d <<= 1)
        mx = fmaxf(mx, __shfl_xor(mx, d));
      float mn = fmaxf(m_r[r], mx);
      alpha[r] = exp2f(m_r[r] - mn);
      m_r[r] = mn;
      mnew[r] = mn;
    }
#pragma unroll
    for (int r = 0; r < 4; r++) {
      float rs = 0.f;
#pragma unroll
      for (int n = 0; n < 4; n++) {
        float p = exp2f(s[n][r] - mnew[r]);
        rs += p;
        p_lds[w][((lane >> 4) * 4 + r) * PSTR + n * 16 + fr] = f2bf(p);
      }
#pragma unroll
      for (int d = 1; d < 16; d <<= 1)
        rs += __shfl_xor(rs, d);
      l_r[r] = l_r[r] * alpha[r] + rs;
    }
#pragma unroll
    for (int nf = 0; nf < 6; nf++)
#pragma unroll
      for (int r = 0; r < 4; r++)
        o[nf][r] *= alpha[r];

    // PV
#pragma unroll
    for (int ks = 0; ks < 2; ks++) {
      bf16x8 pf = *(const bf16x8*)(&p_lds[w][fr * PSTR + ks * 32 + fko]);
#pragma unroll
      for (int nf = 0; nf < 6; nf++) {
        bf16x8 vf = *(const bf16x8*)(&vt_lds[cur][(nf * 16 + fr) * VSTR + ks * 32 + fko]);
        o[nf] = __builtin_amdgcn_mfma_f32_16x16x32_bf16(pf, vf, o[nf], 0, 0, 0);
      }
    }

    if (t + 1 < NT) {
      __syncthreads();   // everyone done reading buf[cur^1] (prev tile)
#pragma unroll
      for (int it = 0; it < 3; it++) {
        *(u32x4*)(&k_lds[cur ^ 1][kl_off[it]]) = kreg[it];
        *(u32x4*)(&vt_lds[cur ^ 1][vl_off[it]]) = vreg[it];
      }
      __syncthreads();   // writes visible before next tile's reads
      cur ^= 1;
    }
  }

  // epilogue: ao[b, l, h*96 + dd], bf16
  const int b = bh >> 3, hh = bh & 7;
#pragma unroll
  for (int r = 0; r < 4; r++) {
    int l = q0 + w * 16 + (lane >> 4) * 4 + r;
    float inv = 1.f / l_r[r];
    size_t base = ((size_t)(b * L + l)) * D + hh * DH;
#pragma unroll
    for (int nf = 0; nf < 6; nf++)
      ao[base + nf * 16 + fr] = f2bf(o[nf][r] * inv);
  }
}

// ---------------------------------------------------------------------------
// Output projection: out = AO @ Wo^T; 64x64 tiles (768 blocks = 3/CU, was
// 192 = 0.75/CU grid-starved). 4 waves as 2x2, each wave 32x32 out.
// ---------------------------------------------------------------------------
__global__ __launch_bounds__(256, 2)
void gemm_out(const u16* __restrict__ A, const float* __restrict__ W,
              float* __restrict__ out)
{
  __shared__ u16 a_lds[64 * 40];
  __shared__ u16 b_lds[64 * 40];
  const int tid = threadIdx.x;
  const int lane = tid & 63;
  const int w = tid >> 6;
  const int wr = w >> 1, wc = w & 1;
  const int row0 = blockIdx.y * 64;
  const int col0 = blockIdx.x * 64;

  f32x4 acc[2][2] = {};
  const int srow = tid >> 2;         // 0..63
  const int scol = (tid & 3) * 8;
  const u16* Ab = A + (size_t)row0 * D;
  const float* Wb = W + (size_t)col0 * D;
  const int fr = lane & 15;
  const int fk = (lane >> 4) * 8;

  for (int k0 = 0; k0 < D; k0 += 32) {
    __syncthreads();
    u32x4 va = *(const u32x4*)(Ab + (size_t)srow * D + k0 + scol);
    bf16x8 vb = cvt8(Wb + (size_t)srow * D + k0 + scol);
    *(u32x4*)(a_lds + srow * 40 + scol) = va;
    *(bf16x8*)(b_lds + srow * 40 + scol) = vb;
    __syncthreads();
    bf16x8 af[2], bfr[2];
#pragma unroll
    for (int m = 0; m < 2; m++)
      af[m] = *(const bf16x8*)(a_lds + (wr * 32 + m * 16 + fr) * 40 + fk);
#pragma unroll
    for (int n = 0; n < 2; n++)
      bfr[n] = *(const bf16x8*)(b_lds + (wc * 32 + n * 16 + fr) * 40 + fk);
#pragma unroll
    for (int m = 0; m < 2; m++)
#pragma unroll
      for (int n = 0; n < 2; n++)
        acc[m][n] = __builtin_amdgcn_mfma_f32_16x16x32_bf16(af[m], bfr[n], acc[m][n], 0, 0, 0);
  }

#pragma unroll
  for (int m = 0; m < 2; m++) {
    int rbase = row0 + wr * 32 + m * 16 + (lane >> 4) * 4;
#pragma unroll
    for (int n = 0; n < 2; n++) {
      int c = col0 + wc * 32 + n * 16 + fr;
#pragma unroll
      for (int r = 0; r < 4; r++)
        out[(size_t)(rbase + r) * D + c] = acc[m][n][r];
    }
  }
}

extern "C" void kernel_launch(void* const* d_in, const int* in_sizes, int n_in,
                              void* d_out, int out_size, void* d_ws, size_t ws_size,
                              hipStream_t stream) {
  (void)in_sizes; (void)n_in; (void)out_size;
  const float* Qin = (const float*)d_in[0];
  const float* Kin = (const float*)d_in[1];
  const float* Vin = (const float*)d_in[2];
  const float* cq  = (const float*)d_in[3];
  const float* ck  = (const float*)d_in[4];
  const float* Wq  = (const float*)d_in[5];
  const float* Wk  = (const float*)d_in[6];
  const float* Wv  = (const float*)d_in[7];
  const float* Wo  = (const float*)d_in[8];
  float* out = (float*)d_out;

  const size_t per = (size_t)NB * H * L * DH;  // 3,145,728 elems
  if (ws_size < 4 * per * sizeof(u16)) return;

  u16* q_ws  = (u16*)d_ws;
  u16* k_ws  = q_ws + per;
  u16* vt_ws = k_ws + per;
  u16* ao_ws = vt_ws + per;

  dim3 blk(256);
  proj_qkv<<<dim3(D / 128, (NB * L) / 128, 3), blk, 0, stream>>>(
      Qin, Kin, Vin, Wq, Wk, Wv, cq, ck, q_ws, k_ws, vt_ws);
  attn_fwd<<<dim3(L / 64, NB * H), blk, 0, stream>>>(q_ws, k_ws, vt_ws, ao_ws);
  gemm_out<<<dim3(D / 64, (NB * L) / 64), blk, 0, stream>>>(ao_ws, Wo, out);
}

// Round 6
// 132.773 us; speedup vs baseline: 1.5671x; 1.1784x over previous
//
#include <hip/hip_runtime.h>
#include <stdint.h>

#define H 8
#define DH 96
#define L 2048
#define NB 2
#define D 768

typedef unsigned short u16;
typedef unsigned int u32;
typedef __attribute__((ext_vector_type(8))) __bf16 bf16x8;
typedef __attribute__((ext_vector_type(4))) float f32x4;
typedef __attribute__((ext_vector_type(4))) u32 u32x4;
typedef __attribute__((ext_vector_type(2))) u32 u32x2;
typedef __attribute__((ext_vector_type(4))) u16 u16x4;

// softmax scale folded with log2(e): 96^-0.5 * 1.4426950408889634
#define QSCALE 0.14724444f

static __device__ __forceinline__ u16 f2bf(float f) {
  union { __bf16 h; u16 u; } v;
  v.h = (__bf16)f;
  return v.u;
}

// load 8 contiguous f32 and round-to-nearest-even to bf16x8
static __device__ __forceinline__ bf16x8 cvt8(const float* p) {
  f32x4 a = *(const f32x4*)p;
  f32x4 b = *(const f32x4*)(p + 4);
  bf16x8 r;
  r[0] = (__bf16)a[0]; r[1] = (__bf16)a[1]; r[2] = (__bf16)a[2]; r[3] = (__bf16)a[3];
  r[4] = (__bf16)b[0]; r[5] = (__bf16)b[1]; r[6] = (__bf16)b[2]; r[7] = (__bf16)b[3];
  return r;
}

// ---------------------------------------------------------------------------
// Fused QKV projection + RoPE (z=0: Q, z=1: K, z=2: V->V^T)  — unchanged.
// ---------------------------------------------------------------------------
__global__ __launch_bounds__(256, 2)
void proj_qkv(const float* __restrict__ Qin, const float* __restrict__ Kin,
              const float* __restrict__ Vin,
              const float* __restrict__ Wq, const float* __restrict__ Wk,
              const float* __restrict__ Wv,
              const float* __restrict__ cq, const float* __restrict__ ck,
              u16* __restrict__ qo, u16* __restrict__ ko, u16* __restrict__ vo)
{
  __shared__ u16 a_lds[128 * 40];
  __shared__ u16 b_lds[128 * 40];
  const int tid = threadIdx.x;
  const int lane = tid & 63;
  const int w = tid >> 6;
  const int wr = w >> 1, wc = w & 1;
  const int z = blockIdx.z;
  const int row0 = blockIdx.y * 128;
  const int col0 = blockIdx.x * 128;

  const float* A = (z == 0) ? Qin : ((z == 1) ? Kin : Vin);
  const float* W = (z == 0) ? Wq : ((z == 1) ? Wk : Wv);

  f32x4 acc[4][4] = {};

  const int srow = tid >> 2;
  const int scol = (tid & 3) * 8;
  const float* Ab = A + (size_t)row0 * D;
  const float* Wb = W + (size_t)col0 * D;
  const int fr = lane & 15;
  const int fk = (lane >> 4) * 8;

  for (int k0 = 0; k0 < D; k0 += 32) {
    __syncthreads();
    bf16x8 va0 = cvt8(Ab + (size_t)srow * D + k0 + scol);
    bf16x8 va1 = cvt8(Ab + (size_t)(srow + 64) * D + k0 + scol);
    bf16x8 vb0 = cvt8(Wb + (size_t)srow * D + k0 + scol);
    bf16x8 vb1 = cvt8(Wb + (size_t)(srow + 64) * D + k0 + scol);
    *(bf16x8*)(a_lds + srow * 40 + scol) = va0;
    *(bf16x8*)(a_lds + (srow + 64) * 40 + scol) = va1;
    *(bf16x8*)(b_lds + srow * 40 + scol) = vb0;
    *(bf16x8*)(b_lds + (srow + 64) * 40 + scol) = vb1;
    __syncthreads();
    bf16x8 af[4], bfr[4];
#pragma unroll
    for (int m = 0; m < 4; m++)
      af[m] = *(const bf16x8*)(a_lds + (wr * 64 + m * 16 + fr) * 40 + fk);
#pragma unroll
    for (int n = 0; n < 4; n++)
      bfr[n] = *(const bf16x8*)(b_lds + (wc * 64 + n * 16 + fr) * 40 + fk);
#pragma unroll
    for (int m = 0; m < 4; m++)
#pragma unroll
      for (int n = 0; n < 4; n++)
        acc[m][n] = __builtin_amdgcn_mfma_f32_16x16x32_bf16(af[m], bfr[n], acc[m][n], 0, 0, 0);
  }

  if (z == 2) {
#pragma unroll
    for (int m = 0; m < 4; m++) {
      int rbase = row0 + wr * 64 + m * 16 + (lane >> 4) * 4;
#pragma unroll
      for (int n = 0; n < 4; n++) {
        int c = col0 + wc * 64 + n * 16 + fr;
        int hh = c / DH, dd = c % DH;
#pragma unroll
        for (int r = 0; r < 4; r++) {
          int row = rbase + r;
          int b = row >> 11, l = row & (L - 1);
          vo[((size_t)((b * H + hh) * DH + dd)) * L + l] = f2bf(acc[m][n][r]);
        }
      }
    }
  } else {
    const float* coords = (z == 0) ? cq : ck;
    u16* outp = (z == 0) ? qo : ko;
    const float postscale = (z == 0) ? QSCALE : 1.0f;
#pragma unroll
    for (int m = 0; m < 4; m++) {
      int rbase = row0 + wr * 64 + m * 16 + (lane >> 4) * 4;
#pragma unroll
      for (int np = 0; np < 2; np++) {
        int n1 = np * 2;
        int c1 = col0 + wc * 64 + n1 * 16 + fr;
        int hh = c1 / DH;
        int dd1 = c1 % DH;
        int axis = dd1 / 32;
        int j = dd1 & 15;
        float invf = exp2f(-(float)j * 0.83048202372184058f);
#pragma unroll
        for (int r = 0; r < 4; r++) {
          int row = rbase + r;
          int b = row >> 11, l = row & (L - 1);
          float coord = coords[((size_t)(b * L + l)) * 3 + axis];
          float ang = coord * invf;
          float sn = __sinf(ang), cs = __cosf(ang);
          float x1 = acc[m][n1][r], x2 = acc[m][n1 + 1][r];
          size_t base = ((size_t)((b * H + hh) * L + l)) * DH;
          outp[base + dd1] = f2bf((x1 * cs - x2 * sn) * postscale);
          outp[base + dd1 + 16] = f2bf((x1 * sn + x2 * cs) * postscale);
        }
      }
    }
  }
}

// ---------------------------------------------------------------------------
// Flash attention, swapped-operand QK^T: s = mfma(K,Q) puts P^T in registers
// (lane fr = q-row; k = kf*16+hi*4+reg across 4 frags). Softmax is lane-local
// (15 VALU + 2 shfl per reduce). P feeds PV's B-operand directly from regs;
// V^T tile columns are permuted at staging (sigma map) so register k-order
// matches the MFMA B-frag sigma-order. No p_lds, 4 shfl/tile instead of 32.
// Register-prefetch + double-buffered K/V LDS retained from r5.
// ---------------------------------------------------------------------------
#define KSTR 104
#define VSTR 72
#define NT   (L / 64)
__global__ __launch_bounds__(256, 2)
void attn_fwd(const u16* __restrict__ q_ws, const u16* __restrict__ k_ws,
              const u16* __restrict__ vt_ws, u16* __restrict__ ao)
{
  __shared__ u16 k_lds[2][64 * KSTR];
  __shared__ u16 vt_lds[2][96 * VSTR];
  const int tid = threadIdx.x;
  const int lane = tid & 63;
  const int w = tid >> 6;
  const int bh = blockIdx.y;
  const int q0 = blockIdx.x * 64;

  const int fr = lane & 15;
  const int hi = lane >> 4;
  const int fko = hi * 8;

  // loop-invariant staging offsets.
  // K: [64][96] -> k_lds rows stride KSTR (natural order).
  // V^T: [96 d-rows][64 k-cols] -> columns permuted by sigma on 4-elem chunks:
  //   chunk q (global cols q*4..q*4+3) lands at col sigma(q)=((q>>3)<<5)|((q&3)<<3)|(((q>>2)&1)<<2)
  int kg_off[3], kl_off[3], vg_off[3], vl0_off[3], vl1_off[3];
#pragma unroll
  for (int it = 0; it < 3; it++) {
    int ch = tid + it * 256;
    int krow = ch / 12, koff = (ch % 12) * 8;
    kg_off[it] = krow * DH + koff;
    kl_off[it] = krow * KSTR + koff;
    int vrow = ch >> 3, vq = (ch & 7) * 2;
    vg_off[it] = vrow * L + vq * 4;
    int s0 = ((vq >> 3) << 5) | ((vq & 3) << 3) | (((vq >> 2) & 1) << 2);
    int vq1 = vq + 1;
    int s1 = ((vq1 >> 3) << 5) | ((vq1 & 3) << 3) | (((vq1 >> 2) & 1) << 2);
    vl0_off[it] = vrow * VSTR + s0;
    vl1_off[it] = vrow * VSTR + s1;
  }

  // Q fragments (B-operand: lane fr = q-row, elements = d at fko+j)
  bf16x8 qf[3];
  const u16* qbase = q_ws + ((size_t)bh * L + q0 + w * 16 + fr) * DH;
#pragma unroll
  for (int ks = 0; ks < 3; ks++)
    qf[ks] = *(const bf16x8*)(qbase + ks * 32 + fko);

  f32x4 o[6] = {};
  float m_r = -1e30f, l_r = 0.f;

  const u16* kbase = k_ws + (size_t)bh * L * DH;
  const u16* vtbase = vt_ws + (size_t)bh * DH * L;

  u32x4 kreg[3], vreg[3];
  // prologue: tile 0 -> regs -> LDS buf 0
#pragma unroll
  for (int it = 0; it < 3; it++) {
    kreg[it] = *(const u32x4*)(kbase + kg_off[it]);
    vreg[it] = *(const u32x4*)(vtbase + vg_off[it]);
  }
#pragma unroll
  for (int it = 0; it < 3; it++) {
    *(u32x4*)(&k_lds[0][kl_off[it]]) = kreg[it];
    u32x2 lo = { vreg[it][0], vreg[it][1] };
    u32x2 hi2 = { vreg[it][2], vreg[it][3] };
    *(u32x2*)(&vt_lds[0][vl0_off[it]]) = lo;
    *(u32x2*)(&vt_lds[0][vl1_off[it]]) = hi2;
  }
  __syncthreads();

  int cur = 0;
  for (int t = 0; t < NT; t++) {
    // prefetch next tile into regs (latency hides under compute)
    if (t + 1 < NT) {
      const u16* kb = kbase + (size_t)(t + 1) * 64 * DH;
      const u16* vb = vtbase + (t + 1) * 64;
#pragma unroll
      for (int it = 0; it < 3; it++) {
        kreg[it] = *(const u32x4*)(kb + kg_off[it]);
        vreg[it] = *(const u32x4*)(vb + vg_off[it]);
      }
    }

    // S^T = K Q^T : lane fr = q, s[kf][reg] = score at k = kf*16+hi*4+reg
    f32x4 s[4] = {};
#pragma unroll
    for (int ks = 0; ks < 3; ks++)
#pragma unroll
      for (int kf = 0; kf < 4; kf++) {
        bf16x8 kfrag = *(const bf16x8*)(&k_lds[cur][(kf * 16 + fr) * KSTR + ks * 32 + fko]);
        s[kf] = __builtin_amdgcn_mfma_f32_16x16x32_bf16(kfrag, qf[ks], s[kf], 0, 0, 0);
      }

    // lane-local online softmax (base-2; q pre-scaled)
    float mx = fmaxf(fmaxf(s[0][0], s[0][1]), fmaxf(s[0][2], s[0][3]));
#pragma unroll
    for (int kf = 1; kf < 4; kf++)
      mx = fmaxf(mx, fmaxf(fmaxf(s[kf][0], s[kf][1]), fmaxf(s[kf][2], s[kf][3])));
    mx = fmaxf(mx, __shfl_xor(mx, 16));
    mx = fmaxf(mx, __shfl_xor(mx, 32));
    float mn = fmaxf(m_r, mx);
    float alpha = exp2f(m_r - mn);
    m_r = mn;

    float p[4][4];
    float rs = 0.f;
#pragma unroll
    for (int kf = 0; kf < 4; kf++)
#pragma unroll
      for (int r = 0; r < 4; r++) {
        float pv = exp2f(s[kf][r] - mn);
        p[kf][r] = pv;
        rs += pv;
      }
    rs += __shfl_xor(rs, 16);
    rs += __shfl_xor(rs, 32);
    l_r = l_r * alpha + rs;

#pragma unroll
    for (int df = 0; df < 6; df++)
#pragma unroll
      for (int r = 0; r < 4; r++)
        o[df][r] *= alpha;

    // build PV B-operand from registers: pt[ks][j] = p[2ks + (j>>2)][j&3]
    bf16x8 pt[2];
#pragma unroll
    for (int ks = 0; ks < 2; ks++)
#pragma unroll
      for (int j = 0; j < 8; j++)
        pt[ks][j] = (__bf16)p[2 * ks + (j >> 2)][j & 3];

    // O^T += V P^T : lane fr = q, o[df][reg] at d = df*16+hi*4+reg
#pragma unroll
    for (int ks = 0; ks < 2; ks++)
#pragma unroll
      for (int df = 0; df < 6; df++) {
        bf16x8 vfrag = *(const bf16x8*)(&vt_lds[cur][(df * 16 + fr) * VSTR + ks * 32 + fko]);
        o[df] = __builtin_amdgcn_mfma_f32_16x16x32_bf16(vfrag, pt[ks], o[df], 0, 0, 0);
      }

    if (t + 1 < NT) {
      __syncthreads();
#pragma unroll
      for (int it = 0; it < 3; it++) {
        *(u32x4*)(&k_lds[cur ^ 1][kl_off[it]]) = kreg[it];
        u32x2 lo = { vreg[it][0], vreg[it][1] };
        u32x2 hi2 = { vreg[it][2], vreg[it][3] };
        *(u32x2*)(&vt_lds[cur ^ 1][vl0_off[it]]) = lo;
        *(u32x2*)(&vt_lds[cur ^ 1][vl1_off[it]]) = hi2;
      }
      __syncthreads();
      cur ^= 1;
    }
  }

  // epilogue: lane fr = q-row; 6 packed b64 stores of 4 contiguous d each
  const int b = bh >> 3, hh = bh & 7;
  const int l = q0 + w * 16 + fr;
  const float inv = 1.f / l_r;
  u16* aop = ao + ((size_t)(b * L + l)) * D + hh * DH + hi * 4;
#pragma unroll
  for (int df = 0; df < 6; df++) {
    u16x4 pk;
#pragma unroll
    for (int r = 0; r < 4; r++)
      pk[r] = f2bf(o[df][r] * inv);
    *(u16x4*)(aop + df * 16) = pk;
  }
}

// ---------------------------------------------------------------------------
// Output projection: out = AO @ Wo^T; 64x64 tiles — unchanged.
// ---------------------------------------------------------------------------
__global__ __launch_bounds__(256, 2)
void gemm_out(const u16* __restrict__ A, const float* __restrict__ W,
              float* __restrict__ out)
{
  __shared__ u16 a_lds[64 * 40];
  __shared__ u16 b_lds[64 * 40];
  const int tid = threadIdx.x;
  const int lane = tid & 63;
  const int w = tid >> 6;
  const int wr = w >> 1, wc = w & 1;
  const int row0 = blockIdx.y * 64;
  const int col0 = blockIdx.x * 64;

  f32x4 acc[2][2] = {};
  const int srow = tid >> 2;
  const int scol = (tid & 3) * 8;
  const u16* Ab = A + (size_t)row0 * D;
  const float* Wb = W + (size_t)col0 * D;
  const int fr = lane & 15;
  const int fk = (lane >> 4) * 8;

  for (int k0 = 0; k0 < D; k0 += 32) {
    __syncthreads();
    u32x4 va = *(const u32x4*)(Ab + (size_t)srow * D + k0 + scol);
    bf16x8 vb = cvt8(Wb + (size_t)srow * D + k0 + scol);
    *(u32x4*)(a_lds + srow * 40 + scol) = va;
    *(bf16x8*)(b_lds + srow * 40 + scol) = vb;
    __syncthreads();
    bf16x8 af[2], bfr[2];
#pragma unroll
    for (int m = 0; m < 2; m++)
      af[m] = *(const bf16x8*)(a_lds + (wr * 32 + m * 16 + fr) * 40 + fk);
#pragma unroll
    for (int n = 0; n < 2; n++)
      bfr[n] = *(const bf16x8*)(b_lds + (wc * 32 + n * 16 + fr) * 40 + fk);
#pragma unroll
    for (int m = 0; m < 2; m++)
#pragma unroll
      for (int n = 0; n < 2; n++)
        acc[m][n] = __builtin_amdgcn_mfma_f32_16x16x32_bf16(af[m], bfr[n], acc[m][n], 0, 0, 0);
  }

#pragma unroll
  for (int m = 0; m < 2; m++) {
    int rbase = row0 + wr * 32 + m * 16 + (lane >> 4) * 4;
#pragma unroll
    for (int n = 0; n < 2; n++) {
      int c = col0 + wc * 32 + n * 16 + fr;
#pragma unroll
      for (int r = 0; r < 4; r++)
        out[(size_t)(rbase + r) * D + c] = acc[m][n][r];
    }
  }
}

extern "C" void kernel_launch(void* const* d_in, const int* in_sizes, int n_in,
                              void* d_out, int out_size, void* d_ws, size_t ws_size,
                              hipStream_t stream) {
  (void)in_sizes; (void)n_in; (void)out_size;
  const float* Qin = (const float*)d_in[0];
  const float* Kin = (const float*)d_in[1];
  const float* Vin = (const float*)d_in[2];
  const float* cq  = (const float*)d_in[3];
  const float* ck  = (const float*)d_in[4];
  const float* Wq  = (const float*)d_in[5];
  const float* Wk  = (const float*)d_in[6];
  const float* Wv  = (const float*)d_in[7];
  const float* Wo  = (const float*)d_in[8];
  float* out = (float*)d_out;

  const size_t per = (size_t)NB * H * L * DH;  // 3,145,728 elems
  if (ws_size < 4 * per * sizeof(u16)) return;

  u16* q_ws  = (u16*)d_ws;
  u16* k_ws  = q_ws + per;
  u16* vt_ws = k_ws + per;
  u16* ao_ws = vt_ws + per;

  dim3 blk(256);
  proj_qkv<<<dim3(D / 128, (NB * L) / 128, 3), blk, 0, stream>>>(
      Qin, Kin, Vin, Wq, Wk, Wv, cq, ck, q_ws, k_ws, vt_ws);
  attn_fwd<<<dim3(L / 64, NB * H), blk, 0, stream>>>(q_ws, k_ws, vt_ws, ao_ws);
  gemm_out<<<dim3(D / 64, (NB * L) / 64), blk, 0, stream>>>(ao_ws, Wo, out);
}